// Round 2
// baseline (23.610 us; speedup 1.0000x reference)
//
#include <hip/hip_runtime.h>

#define KAPPA 0.276f
#define NTRI 8256        // 128*129/2
#define NTRI4 2064       // NTRI/4
#define BATCH 1024
#define TSIZE 8448       // padded transposed triangle size (floats)

// column start of transposed-packed triangle; column k holds i=k..127,
// padded to a multiple of 4 floats (pad = k&3). All cs(k) are multiples of 4.
__device__ __forceinline__ int col_start(int k) {
    int q = k >> 2, r = k & 3;
    int S = 6 * q + ((r == 3) ? 3 : ((r == 2) ? 1 : 0));   // sum_{j<k} (j&3)
    return 128 * k - ((k * (k - 1)) >> 1) + S;
}

__global__ __launch_bounds__(256) void trace_kernel(const float* __restrict__ net_out,
                                                    const float* __restrict__ U1,
                                                    float* __restrict__ ws) {
    const int b = blockIdx.x;
    const int tid = threadIdx.x;

    __shared__ __align__(16) float T[TSIZE];
    __shared__ float red[4];

    // ---- stage packed triangle -> transposed padded LDS; accumulate sum sq ----
    const float4* __restrict__ src = (const float4*)(net_out + (size_t)b * NTRI);
    float sq = 0.f;
    for (int it = 0; it < 9; ++it) {
        int f4 = tid + (it << 8);
        if (f4 < NTRI4) {
            float4 v = src[f4];
            float vv[4] = {v.x, v.y, v.z, v.w};
            int j = f4 << 2;
            #pragma unroll
            for (int e = 0; e < 4; ++e) {
                int je = j + e;
                // row decode: i = floor((sqrt(8j+1)-1)/2), then exact fixup
                float s = sqrtf(8.0f * (float)je + 1.0f);
                int i = (int)((s - 1.0f) * 0.5f);
                int tri = (i * (i + 1)) >> 1;
                if (tri > je)                { --i; tri -= i + 1; }
                else if (tri + i + 1 <= je) { tri += i + 1; ++i; }
                int k = je - tri;
                T[col_start(k) + (i - k)] = vv[e];
            }
            sq += v.x * v.x + v.y * v.y + v.z * v.z + v.w * v.w;
        }
    }
    __syncthreads();

    // ---- each thread: one (column k, direction) contiguous dot product ----
    const int dir = tid >> 7;
    const int k   = tid & 127;
    const int k2  = dir ? ((k & 0x70) | ((k + 2) & 15)) : ((k + 16) & 127);
    const int kmax = (k > k2) ? k : k2;
    const float theta = U1[(size_t)b * 128 + (dir << 6) + ((k >> 4) << 3) + ((k >> 1) & 7)];
    const float coeff = -2.0f * KAPPA * cosf(theta);

    const int csk  = col_start(k);
    const int csk2 = col_start(k2);
    const int d    = k - k2;            // dir0: -16 or +112 (mult of 4); dir1: -2 or +14 (even)

    // groups: o = i - k = 4g, g in [g0, g1]; element i = k + 4g + e
    const int g0 = (kmax - k) >> 2;
    const int g1 = (127 - k) >> 2;

    float ax = 0.f, ay = 0.f, az = 0.f, aw = 0.f;
    const float4* A4 = (const float4*)(T + csk);

    if (dir == 0) {
        const float4* B4 = (const float4*)(T + csk2 + d);
        {   // first group: mask i>=kmax and i<=127
            int i0 = k + (g0 << 2);
            float4 a = A4[g0], bb = B4[g0];
            ax += (i0 + 0 >= kmax && i0 + 0 <= 127) ? a.x * bb.x : 0.f;
            ay += (i0 + 1 >= kmax && i0 + 1 <= 127) ? a.y * bb.y : 0.f;
            az += (i0 + 2 >= kmax && i0 + 2 <= 127) ? a.z * bb.z : 0.f;
            aw += (i0 + 3 >= kmax && i0 + 3 <= 127) ? a.w * bb.w : 0.f;
        }
        #pragma unroll 4
        for (int g = g0 + 1; g < g1; ++g) {
            float4 a = A4[g], bb = B4[g];
            ax += a.x * bb.x; ay += a.y * bb.y; az += a.z * bb.z; aw += a.w * bb.w;
        }
        if (g1 > g0) {   // last group: mask i<=127
            int i0 = k + (g1 << 2);
            float4 a = A4[g1], bb = B4[g1];
            ax += (i0 + 0 <= 127) ? a.x * bb.x : 0.f;
            ay += (i0 + 1 <= 127) ? a.y * bb.y : 0.f;
            az += (i0 + 2 <= 127) ? a.z * bb.z : 0.f;
            aw += (i0 + 3 <= 127) ? a.w * bb.w : 0.f;
        }
    } else {
        const float2* B2 = (const float2*)(T + csk2 + d);   // 8B-aligned (d even)
        {
            int i0 = k + (g0 << 2);
            float4 a = A4[g0];
            float2 b0 = B2[2 * g0], b1 = B2[2 * g0 + 1];
            ax += (i0 + 0 >= kmax && i0 + 0 <= 127) ? a.x * b0.x : 0.f;
            ay += (i0 + 1 >= kmax && i0 + 1 <= 127) ? a.y * b0.y : 0.f;
            az += (i0 + 2 >= kmax && i0 + 2 <= 127) ? a.z * b1.x : 0.f;
            aw += (i0 + 3 >= kmax && i0 + 3 <= 127) ? a.w * b1.y : 0.f;
        }
        #pragma unroll 4
        for (int g = g0 + 1; g < g1; ++g) {
            float4 a = A4[g];
            float2 b0 = B2[2 * g], b1 = B2[2 * g + 1];
            ax += a.x * b0.x; ay += a.y * b0.y; az += a.z * b1.x; aw += a.w * b1.y;
        }
        if (g1 > g0) {
            int i0 = k + (g1 << 2);
            float4 a = A4[g1];
            float2 b0 = B2[2 * g1], b1 = B2[2 * g1 + 1];
            ax += (i0 + 0 <= 127) ? a.x * b0.x : 0.f;
            ay += (i0 + 1 <= 127) ? a.y * b0.y : 0.f;
            az += (i0 + 2 <= 127) ? a.z * b1.x : 0.f;
            aw += (i0 + 3 <= 127) ? a.w * b1.y : 0.f;
        }
    }

    float val = sq + coeff * (ax + ay + az + aw);

    // ---- block reduction (4 waves of 64) ----
    #pragma unroll
    for (int off = 32; off > 0; off >>= 1)
        val += __shfl_down(val, off, 64);
    if ((tid & 63) == 0) red[tid >> 6] = val;
    __syncthreads();
    if (tid == 0)
        ws[b] = red[0] + red[1] + red[2] + red[3];
}

__global__ __launch_bounds__(256) void reduce_kernel(const float* __restrict__ ws,
                                                     float* __restrict__ out) {
    const int tid = threadIdx.x;
    float v = 0.f;
    for (int i = tid; i < BATCH; i += 256) v += ws[i];
    #pragma unroll
    for (int off = 32; off > 0; off >>= 1)
        v += __shfl_down(v, off, 64);
    __shared__ float red[4];
    if ((tid & 63) == 0) red[tid >> 6] = v;
    __syncthreads();
    if (tid == 0)
        out[0] = (red[0] + red[1] + red[2] + red[3]) * (1.0f / (128.0f * (float)BATCH));
}

extern "C" void kernel_launch(void* const* d_in, const int* in_sizes, int n_in,
                              void* d_out, int out_size, void* d_ws, size_t ws_size,
                              hipStream_t stream) {
    const float* net_out = (const float*)d_in[0];  // (1024, 8256) fp32
    const float* U1      = (const float*)d_in[1];  // (1024, 2, 8, 8) fp32
    float* out = (float*)d_out;                    // scalar fp32
    float* ws  = (float*)d_ws;                     // >= 1024 floats

    trace_kernel<<<BATCH, 256, 0, stream>>>(net_out, U1, ws);
    reduce_kernel<<<1, 256, 0, stream>>>(ws, out);
}